// Round 1
// baseline (344.434 us; speedup 1.0000x reference)
//
#include <hip/hip_runtime.h>

typedef __attribute__((ext_vector_type(8))) short short8;
typedef __attribute__((ext_vector_type(4))) float f32x4;

#define MFMA16(a,b,c) __builtin_amdgcn_mfma_f32_16x16x32_bf16((a),(b),(c),0,0,0)

#define BB 32
#define SS 1024
#define DD 192
#define HH 8
#define DHP 32   // padded head dim (24 -> 32)

__device__ __forceinline__ short f2bf(float f) {
    union { float f; unsigned u; } v; v.f = f;
    unsigned r = v.u + 0x7FFFu + ((v.u >> 16) & 1u);   // RNE
    return (short)(r >> 16);
}
__device__ __forceinline__ float bf2f(short s) {
    union { unsigned u; float f; } v; v.u = ((unsigned)(unsigned short)s) << 16;
    return v.f;
}

// ---------------- prep: mask normalize + weight transposes ----------------
__global__ __launch_bounds__(256) void prep_kernel(
    const void* __restrict__ mask_raw,
    const float* __restrict__ Wq, const float* __restrict__ Wk, const float* __restrict__ Wv,
    const float* __restrict__ Wo,
    float* __restrict__ maskf,
    short* __restrict__ WqT, short* __restrict__ WkT, short* __restrict__ WvT,
    short* __restrict__ WoTh, short* __restrict__ WoTl)
{
    int idx = blockIdx.x * 256 + threadIdx.x;
    const int NMASK = BB * SS;               // 32768
    const int NWX   = 3 * HH * DHP * DD;     // 147456
    const int NWO   = DD * DD;               // 36864
    if (idx < NMASK) {
        // dtype sniff: bool may arrive as int32 (0/1), float32 (0.0/1.0) or uint8
        const unsigned* mw = (const unsigned*)mask_raw;
        bool all01 = true, allf = true;
        #pragma unroll
        for (int i = 0; i < 16; i++) {
            unsigned w = mw[i];
            all01 = all01 && (w <= 1u);
            allf  = allf  && (w == 0u || w == 0x3F800000u);
        }
        float m;
        if (all01)      m = (mw[idx] != 0u) ? 1.f : 0.f;
        else if (allf)  m = (((const float*)mask_raw)[idx] != 0.f) ? 1.f : 0.f;
        else            m = (((const unsigned char*)mask_raw)[idx] != 0) ? 1.f : 0.f;
        maskf[idx] = m;
    } else if (idx < NMASK + NWX) {
        int j = idx - NMASK;
        int mat = j / (HH * DHP * DD);
        int jj  = j % (HH * DHP * DD);
        int h   = jj / (DHP * DD);
        int rem = jj % (DHP * DD);
        int e   = rem / DD;
        int d   = rem % DD;
        const float* W = (mat == 0) ? Wq : (mat == 1) ? Wk : Wv;
        short* WT      = (mat == 0) ? WqT : (mat == 1) ? WkT : WvT;
        float val = (e < 24) ? W[(h * DD + d) * 24 + e] : 0.f;   // pad e>=24 with 0
        WT[(h * DHP + e) * DD + d] = f2bf(val);
    } else if (idx < NMASK + NWX + NWO) {
        int j = idx - NMASK - NWX;
        int n = j / DD, k = j % DD;
        float f = Wo[k * DD + n];
        short hi = f2bf(f);
        WoTh[n * DD + k] = hi;
        WoTl[n * DD + k] = f2bf(f - bf2f(hi));   // split-bf16 low part
    }
}

// ---------------- proj: Q/K/V = x @ W + b via MFMA ----------------
__global__ __launch_bounds__(256) void proj_kernel(
    const float* __restrict__ x,
    const float* __restrict__ bq, const float* __restrict__ bk, const float* __restrict__ bv,
    const short* __restrict__ WqT, const short* __restrict__ WkT, const short* __restrict__ WvT,
    short* __restrict__ Q, short* __restrict__ K, short* __restrict__ Vt)
{
    int tid = threadIdx.x;
    int lane = tid & 63, w = tid >> 6;
    int c = lane & 15, g = lane >> 4;
    int r0 = blockIdx.x * 64 + w * 16;
    int arow = r0 + c;

    // A fragments (x rows, bf16-converted), shared across all heads/mats
    short8 a[6];
    #pragma unroll
    for (int kk = 0; kk < 6; kk++) {
        const float* px = x + (size_t)arow * DD + kk * 32 + g * 8;
        float4 f0 = *(const float4*)px;
        float4 f1 = *(const float4*)(px + 4);
        short8 t;
        t[0]=f2bf(f0.x); t[1]=f2bf(f0.y); t[2]=f2bf(f0.z); t[3]=f2bf(f0.w);
        t[4]=f2bf(f1.x); t[5]=f2bf(f1.y); t[6]=f2bf(f1.z); t[7]=f2bf(f1.w);
        a[kk] = t;
    }

    for (int h = 0; h < HH; h++) {
        #pragma unroll
        for (int mat = 0; mat < 3; mat++) {
            const short* WT   = (mat==0)?WqT:(mat==1)?WkT:WvT;
            const float* bias = (mat==0)?bq:(mat==1)?bk:bv;
            #pragma unroll
            for (int nt = 0; nt < 2; nt++) {
                f32x4 acc = {0.f,0.f,0.f,0.f};
                const short* Wp = WT + (size_t)(h * DHP + nt*16 + c) * DD + g * 8;
                #pragma unroll
                for (int kk = 0; kk < 6; kk++) {
                    short8 b = *(const short8*)(Wp + kk * 32);
                    acc = MFMA16(a[kk], b, acc);
                }
                int col = nt*16 + c;
                float bval = (col < 24) ? bias[h*24 + col] : 0.f;
                #pragma unroll
                for (int r = 0; r < 4; r++) {
                    int R = r0 + g*4 + r;
                    int b_ = R >> 10, s_ = R & 1023;
                    int bh = b_ * HH + h;
                    short v = f2bf(acc[r] + bval);
                    if (mat == 2)      Vt[((size_t)bh * DHP + col) * SS + s_] = v;  // V transposed
                    else if (mat == 0) Q[((size_t)bh * SS + s_) * DHP + col] = v;
                    else               K[((size_t)bh * SS + s_) * DHP + col] = v;
                }
            }
        }
    }
}

// ---------------- flash attention ----------------
__global__ __launch_bounds__(256) void flash_kernel(
    const short* __restrict__ Q, const short* __restrict__ K, const short* __restrict__ Vt,
    const float* __restrict__ maskf, float* __restrict__ attn)
{
    __shared__ __align__(16) float mlds[SS];
    __shared__ __align__(16) short P[4][2][16][40];   // pad 40 to spread banks

    // XCD-affine swizzle: all 8 q-blocks of one (b,h) land on one XCD
    int idx = blockIdx.x;
    int bh_lo = idx & 7;
    int t = idx >> 3;
    int bh_hi = t & 31;
    int qb = t >> 5;
    int bh = bh_hi * 8 + bh_lo;
    int b = bh >> 3, h = bh & 7;

    int tid = threadIdx.x;
    int lane = tid & 63, w = tid >> 6;
    int c = lane & 15, g = lane >> 4;

    ((float4*)mlds)[tid] = ((const float4*)(maskf + b * SS))[tid];
    __syncthreads();

    const short* Qh = Q + (size_t)bh * SS * DHP;
    const short* Kh = K + (size_t)bh * SS * DHP;
    const short* Vh = Vt + (size_t)bh * DHP * SS;
    int qr = qb * 128 + w * 32;

    short8 aq[2];
    #pragma unroll
    for (int mt = 0; mt < 2; mt++)
        aq[mt] = *(const short8*)(Qh + (size_t)(qr + mt*16 + c) * DHP + g * 8);

    f32x4 acc[2][2];
    float mrow[2][4], lrow[2][4];
    #pragma unroll
    for (int mt = 0; mt < 2; mt++) {
        #pragma unroll
        for (int n = 0; n < 2; n++) acc[mt][n] = (f32x4){0.f,0.f,0.f,0.f};
        #pragma unroll
        for (int r = 0; r < 4; r++) { mrow[mt][r] = -3e38f; lrow[mt][r] = 0.f; }
    }

    const float SC  = 1.4426950408889634f / 4.898979485566356f;  // log2e / sqrt(24)
    const float NEG = -1.4426950408889634e9f;                    // -1e9 * log2e

    for (int kt = 0; kt < 32; kt++) {
        int t0 = kt * 32;
        short8 bk0 = *(const short8*)(Kh + (size_t)(t0 + c) * DHP + g * 8);
        short8 bk1 = *(const short8*)(Kh + (size_t)(t0 + 16 + c) * DHP + g * 8);
        short8 bv0 = *(const short8*)(Vh + (size_t)(c) * SS + t0 + g * 8);
        short8 bv1 = *(const short8*)(Vh + (size_t)(16 + c) * SS + t0 + g * 8);
        float mf0 = mlds[t0 + c], mf1 = mlds[t0 + 16 + c];

        f32x4 z = {0.f,0.f,0.f,0.f};
        f32x4 sc[2][2];
        sc[0][0] = MFMA16(aq[0], bk0, z);
        sc[0][1] = MFMA16(aq[0], bk1, z);
        sc[1][0] = MFMA16(aq[1], bk0, z);
        sc[1][1] = MFMA16(aq[1], bk1, z);

        float tl[2][2][4];
        #pragma unroll
        for (int mt = 0; mt < 2; mt++) {
            #pragma unroll
            for (int r = 0; r < 4; r++) {
                tl[mt][0][r] = (mf0 != 0.f) ? sc[mt][0][r] * SC : NEG;
                tl[mt][1][r] = (mf1 != 0.f) ? sc[mt][1][r] * SC : NEG;
            }
        }

        float p[2][2][4];
        #pragma unroll
        for (int mt = 0; mt < 2; mt++) {
            float tm[4];
            #pragma unroll
            for (int r = 0; r < 4; r++) tm[r] = fmaxf(tl[mt][0][r], tl[mt][1][r]);
            #pragma unroll
            for (int d = 1; d < 16; d <<= 1) {
                #pragma unroll
                for (int r = 0; r < 4; r++) tm[r] = fmaxf(tm[r], __shfl_xor(tm[r], d));
            }
            float ps[4];
            #pragma unroll
            for (int r = 0; r < 4; r++) {
                float mn = fmaxf(mrow[mt][r], tm[r]);
                float al = __builtin_amdgcn_exp2f(mrow[mt][r] - mn);
                mrow[mt][r] = mn;
                lrow[mt][r] *= al;
                p[mt][0][r] = __builtin_amdgcn_exp2f(tl[mt][0][r] - mn);
                p[mt][1][r] = __builtin_amdgcn_exp2f(tl[mt][1][r] - mn);
                acc[mt][0][r] *= al;
                acc[mt][1][r] *= al;
                ps[r] = p[mt][0][r] + p[mt][1][r];
            }
            #pragma unroll
            for (int d = 1; d < 16; d <<= 1) {
                #pragma unroll
                for (int r = 0; r < 4; r++) ps[r] += __shfl_xor(ps[r], d);
            }
            #pragma unroll
            for (int r = 0; r < 4; r++) lrow[mt][r] += ps[r];
            // P -> LDS (re-layout C-frag -> A-frag)
            #pragma unroll
            for (int r = 0; r < 4; r++) {
                P[w][mt][g*4 + r][c]      = f2bf(p[mt][0][r]);
                P[w][mt][g*4 + r][16 + c] = f2bf(p[mt][1][r]);
            }
        }
        // intra-wave LDS write->read: same-wave DS ops are in-order; compiler
        // preserves order (may-alias) and inserts lgkmcnt before use.
        #pragma unroll
        for (int mt = 0; mt < 2; mt++) {
            short8 pa = *(const short8*)&P[w][mt][c][g * 8];
            acc[mt][0] = MFMA16(pa, bv0, acc[mt][0]);
            acc[mt][1] = MFMA16(pa, bv1, acc[mt][1]);
        }
    }

    #pragma unroll
    for (int mt = 0; mt < 2; mt++) {
        #pragma unroll
        for (int n = 0; n < 2; n++) {
            int col = n*16 + c;
            if (col < 24) {
                #pragma unroll
                for (int r = 0; r < 4; r++) {
                    int row = qr + mt*16 + g*4 + r;
                    attn[((size_t)b * SS + row) * DD + h * 24 + col] = acc[mt][n][r] / lrow[mt][r];
                }
            }
        }
    }
}

// ---------------- final: out = attn @ Wo + bo (split-bf16 for accuracy) ----------------
__global__ __launch_bounds__(256) void final_kernel(
    const float* __restrict__ attn,
    const short* __restrict__ WoTh, const short* __restrict__ WoTl,
    const float* __restrict__ bo, float* __restrict__ out)
{
    int tid = threadIdx.x;
    int lane = tid & 63, w = tid >> 6;
    int c = lane & 15, g = lane >> 4;
    int r0 = blockIdx.x * 64 + w * 16;
    int arow = r0 + c;

    short8 ah[6], al[6];
    #pragma unroll
    for (int kk = 0; kk < 6; kk++) {
        const float* pa = attn + (size_t)arow * DD + kk * 32 + g * 8;
        float4 f0 = *(const float4*)pa;
        float4 f1 = *(const float4*)(pa + 4);
        float fv[8] = {f0.x,f0.y,f0.z,f0.w,f1.x,f1.y,f1.z,f1.w};
        short8 th, tlo;
        #pragma unroll
        for (int j = 0; j < 8; j++) {
            short hi = f2bf(fv[j]);
            th[j] = hi;
            tlo[j] = f2bf(fv[j] - bf2f(hi));
        }
        ah[kk] = th; al[kk] = tlo;
    }

    f32x4 acc[12];
    #pragma unroll
    for (int n = 0; n < 12; n++) acc[n] = (f32x4){0.f,0.f,0.f,0.f};

    #pragma unroll
    for (int kk = 0; kk < 6; kk++) {
        #pragma unroll
        for (int n = 0; n < 12; n++) {
            const short* bh_p = WoTh + (size_t)(n*16 + c) * DD + kk * 32 + g * 8;
            const short* bl_p = WoTl + (size_t)(n*16 + c) * DD + kk * 32 + g * 8;
            short8 bh = *(const short8*)bh_p;
            short8 bl = *(const short8*)bl_p;
            acc[n] = MFMA16(ah[kk], bh, acc[n]);
            acc[n] = MFMA16(al[kk], bh, acc[n]);
            acc[n] = MFMA16(ah[kk], bl, acc[n]);
        }
    }

    #pragma unroll
    for (int n = 0; n < 12; n++) {
        int col = n*16 + c;
        float bv = bo[col];
        #pragma unroll
        for (int r = 0; r < 4; r++) {
            out[(size_t)(r0 + g*4 + r) * DD + col] = acc[n][r] + bv;
        }
    }
}

extern "C" void kernel_launch(void* const* d_in, const int* in_sizes, int n_in,
                              void* d_out, int out_size, void* d_ws, size_t ws_size,
                              hipStream_t stream)
{
    const float* x    = (const float*)d_in[0];
    const void*  mask = d_in[1];
    const float* Wq   = (const float*)d_in[2];
    const float* bq   = (const float*)d_in[3];
    const float* Wk   = (const float*)d_in[4];
    const float* bk   = (const float*)d_in[5];
    const float* Wv   = (const float*)d_in[6];
    const float* bv   = (const float*)d_in[7];
    const float* Wo   = (const float*)d_in[8];
    const float* bo   = (const float*)d_in[9];
    float* out = (float*)d_out;

    // workspace layout (needs ~76 MB)
    char* ws = (char*)d_ws;
    size_t off = 0;
    float* maskf = (float*)(ws + off); off += (size_t)BB*SS*4;          // 128 KB
    short* Q     = (short*)(ws + off); off += (size_t)BB*HH*SS*DHP*2;   // 16 MB
    short* K     = (short*)(ws + off); off += (size_t)BB*HH*SS*DHP*2;   // 16 MB
    short* Vt    = (short*)(ws + off); off += (size_t)BB*HH*SS*DHP*2;   // 16 MB
    float* attn  = (float*)(ws + off); off += (size_t)BB*SS*DD*4;       // 24 MB
    short* WqT   = (short*)(ws + off); off += (size_t)HH*DHP*DD*2;
    short* WkT   = (short*)(ws + off); off += (size_t)HH*DHP*DD*2;
    short* WvT   = (short*)(ws + off); off += (size_t)HH*DHP*DD*2;
    short* WoTh  = (short*)(ws + off); off += (size_t)DD*DD*2;
    short* WoTl  = (short*)(ws + off); off += (size_t)DD*DD*2;

    prep_kernel<<<dim3(848), dim3(256), 0, stream>>>(
        mask, Wq, Wk, Wv, Wo, maskf, WqT, WkT, WvT, WoTh, WoTl);
    proj_kernel<<<dim3(512), dim3(256), 0, stream>>>(
        x, bq, bk, bv, WqT, WkT, WvT, Q, K, Vt);
    flash_kernel<<<dim3(2048), dim3(256), 0, stream>>>(
        Q, K, Vt, maskf, attn);
    final_kernel<<<dim3(512), dim3(256), 0, stream>>>(
        attn, WoTh, WoTl, bo, out);
}

// Round 3
// 218.115 us; speedup vs baseline: 1.5791x; 1.5791x over previous
//
#include <hip/hip_runtime.h>

typedef __attribute__((ext_vector_type(8))) short short8;
typedef __attribute__((ext_vector_type(4))) float f32x4;
typedef __attribute__((ext_vector_type(16))) float f32x16;
typedef __attribute__((ext_vector_type(4))) unsigned uint4v;

#define MFMA16(a,b,c) __builtin_amdgcn_mfma_f32_16x16x32_bf16((a),(b),(c),0,0,0)
#define MFMA32(a,b,c) __builtin_amdgcn_mfma_f32_32x32x16_bf16((a),(b),(c),0,0,0)

#define BB 32
#define SS 1024
#define DD 192
#define HH 8
#define DHP 32   // padded head dim (24 -> 32); col 31 = mask-bias channel

// Q pre-scale: log2(e) / sqrt(24)  -> exp2(S) == softmax numerator
#define SCALE_Q 0.294468266742895f

__device__ __forceinline__ short f2bf(float f) {
    union { float f; unsigned u; } v; v.f = f;
    unsigned r = v.u + 0x7FFFu + ((v.u >> 16) & 1u);   // RNE
    return (short)(r >> 16);
}
__device__ __forceinline__ float bf2f(short s) {
    union { unsigned u; float f; } v; v.u = ((unsigned)(unsigned short)s) << 16;
    return v.f;
}
__device__ __forceinline__ unsigned pk2(float a, float b) {
    return (unsigned)(unsigned short)f2bf(a) | ((unsigned)(unsigned short)f2bf(b) << 16);
}

// ---------------- prep: mask normalize + weight transposes ----------------
__global__ __launch_bounds__(256) void prep_kernel(
    const void* __restrict__ mask_raw,
    const float* __restrict__ Wq, const float* __restrict__ Wk, const float* __restrict__ Wv,
    const float* __restrict__ Wo,
    float* __restrict__ maskf,
    short* __restrict__ WqT, short* __restrict__ WkT, short* __restrict__ WvT,
    short* __restrict__ WoTh, short* __restrict__ WoTl)
{
    int idx = blockIdx.x * 256 + threadIdx.x;
    const int NMASK = BB * SS;               // 32768
    const int NWX   = 3 * HH * DHP * DD;     // 147456
    const int NWO   = DD * DD;               // 36864
    if (idx < NMASK) {
        // dtype sniff: bool may arrive as int32 (0/1), float32 (0.0/1.0) or uint8
        const unsigned* mw = (const unsigned*)mask_raw;
        bool all01 = true, allf = true;
        #pragma unroll
        for (int i = 0; i < 16; i++) {
            unsigned w = mw[i];
            all01 = all01 && (w <= 1u);
            allf  = allf  && (w == 0u || w == 0x3F800000u);
        }
        float m;
        if (all01)      m = (mw[idx] != 0u) ? 1.f : 0.f;
        else if (allf)  m = (((const float*)mask_raw)[idx] != 0.f) ? 1.f : 0.f;
        else            m = (((const unsigned char*)mask_raw)[idx] != 0) ? 1.f : 0.f;
        maskf[idx] = m;
    } else if (idx < NMASK + NWX) {
        int j = idx - NMASK;
        int mat = j / (HH * DHP * DD);
        int jj  = j % (HH * DHP * DD);
        int h   = jj / (DHP * DD);
        int rem = jj % (DHP * DD);
        int e   = rem / DD;
        int d   = rem % DD;
        const float* W = (mat == 0) ? Wq : (mat == 1) ? Wk : Wv;
        short* WT      = (mat == 0) ? WqT : (mat == 1) ? WkT : WvT;
        float val = (e < 24) ? W[(h * DD + d) * 24 + e] : 0.f;   // pad e>=24 with 0
        WT[(h * DHP + e) * DD + d] = f2bf(val);
    } else if (idx < NMASK + NWX + NWO) {
        int j = idx - NMASK - NWX;
        int n = j / DD, k = j % DD;
        float f = Wo[k * DD + n];
        short hi = f2bf(f);
        WoTh[n * DD + k] = hi;
        WoTl[n * DD + k] = f2bf(f - bf2f(hi));   // split-bf16 low part
    }
}

// ---------------- proj: Q/K/V = x @ W + b via MFMA ----------------
// Q is pre-scaled by SCALE_Q, Q[:,31] = 1.0 (bias channel input)
// K[:,31]   = mask ? 0 : -1e30 (bias channel: QK^T gets -1e30 on masked k)
__global__ __launch_bounds__(256) void proj_kernel(
    const float* __restrict__ x,
    const float* __restrict__ bq, const float* __restrict__ bk, const float* __restrict__ bv,
    const short* __restrict__ WqT, const short* __restrict__ WkT, const short* __restrict__ WvT,
    const float* __restrict__ maskf,
    short* __restrict__ Q, short* __restrict__ K, short* __restrict__ Vt)
{
    int tid = threadIdx.x;
    int lane = tid & 63, w = tid >> 6;
    int c = lane & 15, g = lane >> 4;
    int r0 = blockIdx.x * 64 + w * 16;
    int arow = r0 + c;

    short8 a[6];
    #pragma unroll
    for (int kk = 0; kk < 6; kk++) {
        const float* px = x + (size_t)arow * DD + kk * 32 + g * 8;
        float4 f0 = *(const float4*)px;
        float4 f1 = *(const float4*)(px + 4);
        short8 t;
        t[0]=f2bf(f0.x); t[1]=f2bf(f0.y); t[2]=f2bf(f0.z); t[3]=f2bf(f0.w);
        t[4]=f2bf(f1.x); t[5]=f2bf(f1.y); t[6]=f2bf(f1.z); t[7]=f2bf(f1.w);
        a[kk] = t;
    }

    for (int h = 0; h < HH; h++) {
        #pragma unroll
        for (int mat = 0; mat < 3; mat++) {
            const short* WT   = (mat==0)?WqT:(mat==1)?WkT:WvT;
            const float* bias = (mat==0)?bq:(mat==1)?bk:bv;
            #pragma unroll
            for (int nt = 0; nt < 2; nt++) {
                f32x4 acc = {0.f,0.f,0.f,0.f};
                const short* Wp = WT + (size_t)(h * DHP + nt*16 + c) * DD + g * 8;
                #pragma unroll
                for (int kk = 0; kk < 6; kk++) {
                    short8 b = *(const short8*)(Wp + kk * 32);
                    acc = MFMA16(a[kk], b, acc);
                }
                int col = nt*16 + c;
                float bval = (col < 24) ? bias[h*24 + col] : 0.f;
                #pragma unroll
                for (int r = 0; r < 4; r++) {
                    int R = r0 + g*4 + r;
                    int b_ = R >> 10, s_ = R & 1023;
                    int bh = b_ * HH + h;
                    if (mat == 0) {
                        short v = (col == 31) ? (short)0x3F80
                                              : f2bf((acc[r] + bval) * SCALE_Q);
                        Q[((size_t)bh * SS + s_) * DHP + col] = v;
                    } else if (mat == 1) {
                        short v;
                        if (col == 31) {
                            float m = maskf[b_ * SS + s_];
                            v = (m != 0.f) ? (short)0 : f2bf(-1e30f);
                        } else v = f2bf(acc[r] + bval);
                        K[((size_t)bh * SS + s_) * DHP + col] = v;
                    } else {
                        Vt[((size_t)bh * DHP + col) * SS + s_] = f2bf(acc[r] + bval);
                    }
                }
            }
        }
    }
}

// ---------------- flash attention (swapped QK^T, in-register softmax) ----------------
__global__ __launch_bounds__(256) void flash_kernel(
    const short* __restrict__ Q, const short* __restrict__ K, const short* __restrict__ Vt,
    float* __restrict__ attn)
{
    __shared__ float llds[4][32];

    // XCD-affine swizzle: all 8 q-blocks of one (b,h) land on one XCD
    int idx = blockIdx.x;
    int bh = ((idx >> 3) & 31) * 8 + (idx & 7);
    int qb = idx >> 8;
    int b = bh >> 3, h = bh & 7;

    int tid = threadIdx.x;
    int lane = tid & 63, w = tid >> 6;
    int l31 = lane & 31;
    int hi = lane >> 5;
    bool h1 = (hi != 0);

    int qr = qb * 128 + w * 32;

    // Q B-fragments (col = q = l31, k-dim = head-dim e), loop-invariant
    const short* Qp = Q + ((size_t)bh * SS + qr + l31) * DHP + hi * 8;
    short8 q0 = *(const short8*)Qp;          // e = hi*8 + j
    short8 q1 = *(const short8*)(Qp + 16);   // e = 16 + hi*8 + j

    const short* Kp = K + ((size_t)bh * SS + l31) * DHP + hi * 8;
    const short* Vp = Vt + ((size_t)bh * DHP + l31) * SS + hi * 8;

    f32x16 acc;
    #pragma unroll
    for (int r = 0; r < 16; r++) acc[r] = 0.f;
    float lsum = 0.f;

    for (int kt = 0; kt < 32; kt++) {
        short8 k0 = *(const short8*)(Kp);        // A: row = kpos, kdim e 0..15
        short8 k1 = *(const short8*)(Kp + 16);   //                kdim e 16..31
        short8 v0 = *(const short8*)(Vp);        // B: col = e, k = kpos 0..15
        short8 v1 = *(const short8*)(Vp + 16);   //             k = kpos 16..31
        Kp += 32 * DHP;
        Vp += 32;

        // S[kpos][q]: col = q = l31, row = kpos = (r&3) + 8*(r>>2) + 4*hi
        f32x16 S;
        #pragma unroll
        for (int r = 0; r < 16; r++) S[r] = 0.f;
        S = MFMA32(k0, q0, S);
        S = MFMA32(k1, q1, S);   // includes mask bias via channel e=31

        float p[16];
        #pragma unroll
        for (int r = 0; r < 16; r++) p[r] = __builtin_amdgcn_exp2f(S[r]);

        lsum += (((p[0]+p[1])+(p[2]+p[3])) + ((p[4]+p[5])+(p[6]+p[7])))
              + (((p[8]+p[9])+(p[10]+p[11])) + ((p[12]+p[13])+(p[14]+p[15])));

        // pack P pairs: cXY = bf16(p[X]) | bf16(p[Y])<<16
        // lane (l31, hi) holds P[kpos = (r&3)+8*(r>>2)+4*hi][q = l31]
        unsigned c01 = pk2(p[0],  p[1]);   // kpos {0,1}+4hi
        unsigned c23 = pk2(p[2],  p[3]);   // kpos {2,3}+4hi
        unsigned c45 = pk2(p[4],  p[5]);   // kpos {8,9}+4hi
        unsigned c67 = pk2(p[6],  p[7]);   // kpos {10,11}+4hi
        unsigned c89 = pk2(p[8],  p[9]);   // kpos {16,17}+4hi
        unsigned cab = pk2(p[10], p[11]);  // kpos {18,19}+4hi
        unsigned ccd = pk2(p[12], p[13]);  // kpos {24,25}+4hi
        unsigned cef = pk2(p[14], p[15]);  // kpos {26,27}+4hi

        // counterpart-half values (lane ^ 32)
        unsigned o01 = __shfl_xor(c01, 32);
        unsigned o23 = __shfl_xor(c23, 32);
        unsigned o45 = __shfl_xor(c45, 32);
        unsigned o67 = __shfl_xor(c67, 32);
        unsigned o89 = __shfl_xor(c89, 32);
        unsigned oab = __shfl_xor(cab, 32);
        unsigned ocd = __shfl_xor(ccd, 32);
        unsigned oef = __shfl_xor(cef, 32);

        // PV A-fragment: row = q = l31, k = kpos = hi*8 + j
        // hi=0 needs kpos 0..7:  {0,1}=c01, {2,3}=c23, {4,5}=o01, {6,7}=o23
        // hi=1 needs kpos 8..15: {8,9}=o45, {10,11}=o67, {12,13}=c45, {14,15}=c67
        uint4v w0v = { h1 ? o45 : c01, h1 ? o67 : c23,
                       h1 ? c45 : o01, h1 ? c67 : o23 };
        // hi=0 needs kpos 16..23: {16,17}=c89, {18,19}=cab, {20,21}=o89, {22,23}=oab
        // hi=1 needs kpos 24..31: {24,25}=ocd, {26,27}=oef, {28,29}=ccd, {30,31}=cef
        uint4v w1v = { h1 ? ocd : c89, h1 ? oef : cab,
                       h1 ? ccd : o89, h1 ? cef : oab };
        short8 pa0 = __builtin_bit_cast(short8, w0v);
        short8 pa1 = __builtin_bit_cast(short8, w1v);

        acc = MFMA32(pa0, v0, acc);
        acc = MFMA32(pa1, v1, acc);
    }

    // combine the two kpos-halves of lsum (lane <-> lane^32), then 1/l
    float ltot = lsum + __shfl_xor(lsum, 32);
    llds[w][l31] = 1.0f / ltot;   // indexed by q = l31

    // O: col = e = l31, row = q = (r&3) + 8*(r>>2) + 4*hi
    if (l31 < 24) {
        float* op = attn + ((size_t)b * SS + qr) * DD + h * 24 + l31;
        #pragma unroll
        for (int r = 0; r < 16; r++) {
            int row = (r & 3) + 8 * (r >> 2) + 4 * hi;
            op[(size_t)row * DD] = acc[r] * llds[w][row];
        }
    }
}

// ---------------- final: out = attn @ Wo + bo (split-bf16 for accuracy) ----------------
__global__ __launch_bounds__(256) void final_kernel(
    const float* __restrict__ attn,
    const short* __restrict__ WoTh, const short* __restrict__ WoTl,
    const float* __restrict__ bo, float* __restrict__ out)
{
    int tid = threadIdx.x;
    int lane = tid & 63, w = tid >> 6;
    int c = lane & 15, g = lane >> 4;
    int r0 = blockIdx.x * 64 + w * 16;
    int arow = r0 + c;

    short8 ah[6], al[6];
    #pragma unroll
    for (int kk = 0; kk < 6; kk++) {
        const float* pa = attn + (size_t)arow * DD + kk * 32 + g * 8;
        float4 f0 = *(const float4*)pa;
        float4 f1 = *(const float4*)(pa + 4);
        float fv[8] = {f0.x,f0.y,f0.z,f0.w,f1.x,f1.y,f1.z,f1.w};
        short8 th, tlo;
        #pragma unroll
        for (int j = 0; j < 8; j++) {
            short hi = f2bf(fv[j]);
            th[j] = hi;
            tlo[j] = f2bf(fv[j] - bf2f(hi));
        }
        ah[kk] = th; al[kk] = tlo;
    }

    f32x4 acc[12];
    #pragma unroll
    for (int n = 0; n < 12; n++) acc[n] = (f32x4){0.f,0.f,0.f,0.f};

    #pragma unroll
    for (int kk = 0; kk < 6; kk++) {
        #pragma unroll
        for (int n = 0; n < 12; n++) {
            const short* bh_p = WoTh + (size_t)(n*16 + c) * DD + kk * 32 + g * 8;
            const short* bl_p = WoTl + (size_t)(n*16 + c) * DD + kk * 32 + g * 8;
            short8 bh = *(const short8*)bh_p;
            short8 bl = *(const short8*)bl_p;
            acc[n] = MFMA16(ah[kk], bh, acc[n]);
            acc[n] = MFMA16(al[kk], bh, acc[n]);
            acc[n] = MFMA16(ah[kk], bl, acc[n]);
        }
    }

    #pragma unroll
    for (int n = 0; n < 12; n++) {
        int col = n*16 + c;
        float bv = bo[col];
        #pragma unroll
        for (int r = 0; r < 4; r++) {
            out[(size_t)(r0 + g*4 + r) * DD + col] = acc[n][r] + bv;
        }
    }
}

extern "C" void kernel_launch(void* const* d_in, const int* in_sizes, int n_in,
                              void* d_out, int out_size, void* d_ws, size_t ws_size,
                              hipStream_t stream)
{
    const float* x    = (const float*)d_in[0];
    const void*  mask = d_in[1];
    const float* Wq   = (const float*)d_in[2];
    const float* bq   = (const float*)d_in[3];
    const float* Wk   = (const float*)d_in[4];
    const float* bk   = (const float*)d_in[5];
    const float* Wv   = (const float*)d_in[6];
    const float* bv   = (const float*)d_in[7];
    const float* Wo   = (const float*)d_in[8];
    const float* bo   = (const float*)d_in[9];
    float* out = (float*)d_out;

    char* ws = (char*)d_ws;
    size_t off = 0;
    float* maskf = (float*)(ws + off); off += (size_t)BB*SS*4;          // 128 KB
    short* Q     = (short*)(ws + off); off += (size_t)BB*HH*SS*DHP*2;   // 16 MB
    short* K     = (short*)(ws + off); off += (size_t)BB*HH*SS*DHP*2;   // 16 MB
    short* Vt    = (short*)(ws + off); off += (size_t)BB*HH*SS*DHP*2;   // 16 MB
    float* attn  = (float*)(ws + off); off += (size_t)BB*SS*DD*4;       // 24 MB
    short* WqT   = (short*)(ws + off); off += (size_t)HH*DHP*DD*2;
    short* WkT   = (short*)(ws + off); off += (size_t)HH*DHP*DD*2;
    short* WvT   = (short*)(ws + off); off += (size_t)HH*DHP*DD*2;
    short* WoTh  = (short*)(ws + off); off += (size_t)DD*DD*2;
    short* WoTl  = (short*)(ws + off); off += (size_t)DD*DD*2;

    prep_kernel<<<dim3(848), dim3(256), 0, stream>>>(
        mask, Wq, Wk, Wv, Wo, maskf, WqT, WkT, WvT, WoTh, WoTl);
    proj_kernel<<<dim3(512), dim3(256), 0, stream>>>(
        x, bq, bk, bv, WqT, WkT, WvT, maskf, Q, K, Vt);
    flash_kernel<<<dim3(2048), dim3(256), 0, stream>>>(
        Q, K, Vt, attn);
    final_kernel<<<dim3(512), dim3(256), 0, stream>>>(
        attn, WoTh, WoTl, bo, out);
}

// Round 4
// 196.960 us; speedup vs baseline: 1.7488x; 1.1074x over previous
//
#include <hip/hip_runtime.h>

typedef __attribute__((ext_vector_type(8))) short short8;
typedef __attribute__((ext_vector_type(4))) short short4v;
typedef __attribute__((ext_vector_type(4))) float f32x4;
typedef __attribute__((ext_vector_type(16))) float f32x16;
typedef __attribute__((ext_vector_type(4))) unsigned uint4v;

#define MFMA16(a,b,c) __builtin_amdgcn_mfma_f32_16x16x32_bf16((a),(b),(c),0,0,0)
#define MFMA32(a,b,c) __builtin_amdgcn_mfma_f32_32x32x16_bf16((a),(b),(c),0,0,0)

#define BB 32
#define SS 1024
#define DD 192
#define HH 8
#define DHP 32   // padded head dim (24 -> 32); col 31 = mask-bias channel

// Q pre-scale: log2(e) / sqrt(24)  -> exp2(S) == softmax numerator
#define SCALE_Q 0.294468266742895f

// native RNE conversions (compiler emits v_cvt_*_bf16, fuses pairs to cvt_pk)
__device__ __forceinline__ short nb(float f) {
    __bf16 h = (__bf16)f;
    return __builtin_bit_cast(short, h);
}
__device__ __forceinline__ float bf2f(short s) {
    union { unsigned u; float f; } v; v.u = ((unsigned)(unsigned short)s) << 16;
    return v.f;
}
__device__ __forceinline__ unsigned pk2(float a, float b) {
    unsigned short lo = __builtin_bit_cast(unsigned short, (__bf16)a);
    unsigned short hi = __builtin_bit_cast(unsigned short, (__bf16)b);
    return (unsigned)lo | ((unsigned)hi << 16);
}

// ---------------- prep: mask normalize + weight transposes ----------------
// WqT/WkT/WvT rows within a head are PERMUTED: physical row p holds actual
// col e where p = (e>>1) | ((e&1)<<4)  (so proj pass nt, lane c -> col 2c+nt)
__global__ __launch_bounds__(256) void prep_kernel(
    const void* __restrict__ mask_raw,
    const float* __restrict__ Wq, const float* __restrict__ Wk, const float* __restrict__ Wv,
    const float* __restrict__ Wo,
    float* __restrict__ maskf,
    short* __restrict__ WqT, short* __restrict__ WkT, short* __restrict__ WvT,
    short* __restrict__ WoTh, short* __restrict__ WoTl)
{
    int idx = blockIdx.x * 256 + threadIdx.x;
    const int NMASK = BB * SS;               // 32768
    const int NWX   = 3 * HH * DHP * DD;     // 147456
    const int NWO   = DD * DD;               // 36864
    if (idx < NMASK) {
        // dtype sniff: bool may arrive as int32 (0/1), float32 (0.0/1.0) or uint8
        const unsigned* mw = (const unsigned*)mask_raw;
        bool all01 = true, allf = true;
        #pragma unroll
        for (int i = 0; i < 16; i++) {
            unsigned w = mw[i];
            all01 = all01 && (w <= 1u);
            allf  = allf  && (w == 0u || w == 0x3F800000u);
        }
        float m;
        if (all01)      m = (mw[idx] != 0u) ? 1.f : 0.f;
        else if (allf)  m = (((const float*)mask_raw)[idx] != 0.f) ? 1.f : 0.f;
        else            m = (((const unsigned char*)mask_raw)[idx] != 0) ? 1.f : 0.f;
        maskf[idx] = m;
    } else if (idx < NMASK + NWX) {
        int j = idx - NMASK;
        int mat = j / (HH * DHP * DD);
        int jj  = j % (HH * DHP * DD);
        int h   = jj / (DHP * DD);
        int rem = jj % (DHP * DD);
        int e   = rem / DD;       // actual output col
        int d   = rem % DD;
        const float* W = (mat == 0) ? Wq : (mat == 1) ? Wk : Wv;
        short* WT      = (mat == 0) ? WqT : (mat == 1) ? WkT : WvT;
        float val = (e < 24) ? W[(h * DD + d) * 24 + e] : 0.f;   // pad e>=24 with 0
        int p = (e >> 1) | ((e & 1) << 4);                       // permuted row
        WT[(h * DHP + p) * DD + d] = nb(val);
    } else if (idx < NMASK + NWX + NWO) {
        int j = idx - NMASK - NWX;
        int n = j / DD, k = j % DD;
        float f = Wo[k * DD + n];
        short hi = nb(f);
        WoTh[n * DD + k] = hi;
        WoTl[n * DD + k] = nb(f - bf2f(hi));   // split-bf16 low part
    }
}

// ---------------- proj: Q/K/V = x @ W + b via MFMA ----------------
// Q is pre-scaled by SCALE_Q, Q[:,31] = 1.0 (bias channel input)
// K[:,31]   = mask ? 0 : -1e30 (bias channel: QK^T gets -1e30 on masked k)
__global__ __launch_bounds__(256) void proj_kernel(
    const float* __restrict__ x,
    const float* __restrict__ bq, const float* __restrict__ bk, const float* __restrict__ bv,
    const short* __restrict__ WqT, const short* __restrict__ WkT, const short* __restrict__ WvT,
    const float* __restrict__ maskf,
    short* __restrict__ Q, short* __restrict__ K, short* __restrict__ Vt)
{
    int tid = threadIdx.x;
    int lane = tid & 63, w = tid >> 6;
    int c = lane & 15, g = lane >> 4;
    int r0 = blockIdx.x * 64 + w * 16;
    int arow = r0 + c;

    // output row block for this thread: rows s0..s0+3 (same batch: 64 | 1024)
    int b_ = r0 >> 10;
    int s0 = (r0 & 1023) + g * 4;

    short8 a[6];
    #pragma unroll
    for (int kk = 0; kk < 6; kk++) {
        const float* px = x + (size_t)arow * DD + kk * 32 + g * 8;
        float4 f0 = *(const float4*)px;
        float4 f1 = *(const float4*)(px + 4);
        short8 t;
        t[0]=nb(f0.x); t[1]=nb(f0.y); t[2]=nb(f0.z); t[3]=nb(f0.w);
        t[4]=nb(f1.x); t[5]=nb(f1.y); t[6]=nb(f1.z); t[7]=nb(f1.w);
        a[kk] = t;
    }

    // mask values for this thread's 4 rows (only needed by c==15 for K)
    float mrow[4];
    #pragma unroll
    for (int r = 0; r < 4; r++) mrow[r] = maskf[b_ * SS + s0 + r];

    for (int h = 0; h < HH; h++) {
        int bh = b_ * HH + h;
        #pragma unroll
        for (int mat = 0; mat < 3; mat++) {
            const short* WT   = (mat==0)?WqT:(mat==1)?WkT:WvT;
            const float* bias = (mat==0)?bq:(mat==1)?bk:bv;

            f32x4 acc0 = {0.f,0.f,0.f,0.f};   // actual col 2c
            f32x4 acc1 = {0.f,0.f,0.f,0.f};   // actual col 2c+1
            const short* Wp0 = WT + (size_t)(h * DHP + c) * DD + g * 8;
            const short* Wp1 = WT + (size_t)(h * DHP + 16 + c) * DD + g * 8;
            #pragma unroll
            for (int kk = 0; kk < 6; kk++) {
                short8 b0 = *(const short8*)(Wp0 + kk * 32);
                short8 b1 = *(const short8*)(Wp1 + kk * 32);
                acc0 = MFMA16(a[kk], b0, acc0);
                acc1 = MFMA16(a[kk], b1, acc1);
            }
            // bias for cols 2c, 2c+1 (0 when >= 24)
            float bv0 = 0.f, bv1 = 0.f;
            if (2*c < 24) {
                float2 bb = *(const float2*)(bias + h * 24 + 2 * c);
                bv0 = bb.x; bv1 = bb.y;
            }

            if (mat == 0) {
                #pragma unroll
                for (int r = 0; r < 4; r++) {
                    float v0 = (acc0[r] + bv0) * SCALE_Q;
                    float v1 = (c == 15) ? 1.0f : (acc1[r] + bv1) * SCALE_Q;
                    *(unsigned*)(Q + ((size_t)bh * SS + s0 + r) * DHP + 2*c) = pk2(v0, v1);
                }
            } else if (mat == 1) {
                #pragma unroll
                for (int r = 0; r < 4; r++) {
                    float v0 = acc0[r] + bv0;
                    float v1 = (c == 15) ? ((mrow[r] != 0.f) ? 0.f : -1e30f)
                                         : (acc1[r] + bv1);
                    *(unsigned*)(K + ((size_t)bh * SS + s0 + r) * DHP + 2*c) = pk2(v0, v1);
                }
            } else {
                short4v sv0, sv1;
                #pragma unroll
                for (int r = 0; r < 4; r++) {
                    sv0[r] = nb(acc0[r] + bv0);
                    sv1[r] = nb(acc1[r] + bv1);
                }
                *(short4v*)(Vt + ((size_t)bh * DHP + 2*c) * SS + s0)     = sv0;
                *(short4v*)(Vt + ((size_t)bh * DHP + 2*c + 1) * SS + s0) = sv1;
            }
        }
    }
}

// ---------------- flash attention (swapped QK^T, in-register softmax) ----------------
// softmax-tile processing: exp2, row-sum, pack to bf16, cross-half exchange, PV
__device__ __forceinline__ void fproc(const f32x16& S, f32x16& acc, float& lsum,
                                      short8 v0, short8 v1, bool h1)
{
    float p[16];
    #pragma unroll
    for (int r = 0; r < 16; r++) p[r] = __builtin_amdgcn_exp2f(S[r]);

    lsum += (((p[0]+p[1])+(p[2]+p[3])) + ((p[4]+p[5])+(p[6]+p[7])))
          + (((p[8]+p[9])+(p[10]+p[11])) + ((p[12]+p[13])+(p[14]+p[15])));

    // pack P pairs: lane (l31, hi) holds P[kpos = (r&3)+8*(r>>2)+4*hi][q = l31]
    unsigned c01 = pk2(p[0],  p[1]);   // kpos {0,1}+4hi
    unsigned c23 = pk2(p[2],  p[3]);   // kpos {2,3}+4hi
    unsigned c45 = pk2(p[4],  p[5]);   // kpos {8,9}+4hi
    unsigned c67 = pk2(p[6],  p[7]);   // kpos {10,11}+4hi
    unsigned c89 = pk2(p[8],  p[9]);   // kpos {16,17}+4hi
    unsigned cab = pk2(p[10], p[11]);  // kpos {18,19}+4hi
    unsigned ccd = pk2(p[12], p[13]);  // kpos {24,25}+4hi
    unsigned cef = pk2(p[14], p[15]);  // kpos {26,27}+4hi

    unsigned o01 = __shfl_xor(c01, 32);
    unsigned o23 = __shfl_xor(c23, 32);
    unsigned o45 = __shfl_xor(c45, 32);
    unsigned o67 = __shfl_xor(c67, 32);
    unsigned o89 = __shfl_xor(c89, 32);
    unsigned oab = __shfl_xor(cab, 32);
    unsigned ocd = __shfl_xor(ccd, 32);
    unsigned oef = __shfl_xor(cef, 32);

    // PV A-fragment: row = q = l31, k = kpos = hi*8 + j
    uint4v w0v = { h1 ? o45 : c01, h1 ? o67 : c23,
                   h1 ? c45 : o01, h1 ? c67 : o23 };
    uint4v w1v = { h1 ? ocd : c89, h1 ? oef : cab,
                   h1 ? ccd : o89, h1 ? cef : oab };
    short8 pa0 = __builtin_bit_cast(short8, w0v);
    short8 pa1 = __builtin_bit_cast(short8, w1v);

    acc = MFMA32(pa0, v0, acc);
    acc = MFMA32(pa1, v1, acc);
}

__global__ __launch_bounds__(256) void flash_kernel(
    const short* __restrict__ Q, const short* __restrict__ K, const short* __restrict__ Vt,
    float* __restrict__ attn)
{
    __shared__ float llds[4][2][32];

    // consecutive idx = consecutive bh (round-robin XCD); the 4 q-blocks of
    // one bh are 256 apart -> same XCD (256 % 8 == 0) -> K/V L2 locality
    int idx = blockIdx.x;
    int bh = idx & 255;
    int qb = idx >> 8;          // 0..3
    int b = bh >> 3, h = bh & 7;

    int tid = threadIdx.x;
    int lane = tid & 63, w = tid >> 6;
    int l31 = lane & 31;
    int hi = lane >> 5;
    bool h1 = (hi != 0);

    int qrA = qb * 256 + w * 32;
    int qrB = qrA + 128;

    // Q B-fragments (col = q = l31, k-dim = head-dim e), loop-invariant
    const short* QpA = Q + ((size_t)bh * SS + qrA + l31) * DHP + hi * 8;
    const short* QpB = Q + ((size_t)bh * SS + qrB + l31) * DHP + hi * 8;
    short8 qA0 = *(const short8*)QpA;          // e = hi*8 + j
    short8 qA1 = *(const short8*)(QpA + 16);   // e = 16 + hi*8 + j
    short8 qB0 = *(const short8*)QpB;
    short8 qB1 = *(const short8*)(QpB + 16);

    const short* Kp = K + ((size_t)bh * SS + l31) * DHP + hi * 8;
    const short* Vp = Vt + ((size_t)bh * DHP + l31) * SS + hi * 8;

    f32x16 accA, accB;
    #pragma unroll
    for (int r = 0; r < 16; r++) { accA[r] = 0.f; accB[r] = 0.f; }
    float lsumA = 0.f, lsumB = 0.f;

    for (int kt = 0; kt < 32; kt++) {
        short8 k0 = *(const short8*)(Kp);        // A: row = kpos, kdim e 0..15
        short8 k1 = *(const short8*)(Kp + 16);   //                kdim e 16..31
        short8 v0 = *(const short8*)(Vp);        // B: col = e, k = kpos 0..15
        short8 v1 = *(const short8*)(Vp + 16);   //             k = kpos 16..31
        Kp += 32 * DHP;
        Vp += 32;

        // S[kpos][q]: col = q = l31, row = kpos = (r&3) + 8*(r>>2) + 4*hi
        f32x16 SA, SB;
        #pragma unroll
        for (int r = 0; r < 16; r++) { SA[r] = 0.f; SB[r] = 0.f; }
        SA = MFMA32(k0, qA0, SA);
        SA = MFMA32(k1, qA1, SA);   // includes mask bias via channel e=31
        SB = MFMA32(k0, qB0, SB);
        SB = MFMA32(k1, qB1, SB);

        fproc(SA, accA, lsumA, v0, v1, h1);
        fproc(SB, accB, lsumB, v0, v1, h1);
    }

    // combine the two kpos-halves of lsum (lane <-> lane^32), then 1/l
    float ltotA = lsumA + __shfl_xor(lsumA, 32);
    float ltotB = lsumB + __shfl_xor(lsumB, 32);
    llds[w][0][l31] = 1.0f / ltotA;   // indexed by q = l31
    llds[w][1][l31] = 1.0f / ltotB;

    // O: col = e = l31, row = q = (r&3) + 8*(r>>2) + 4*hi
    if (l31 < 24) {
        float* opA = attn + ((size_t)b * SS + qrA) * DD + h * 24 + l31;
        float* opB = attn + ((size_t)b * SS + qrB) * DD + h * 24 + l31;
        #pragma unroll
        for (int r = 0; r < 16; r++) {
            int row = (r & 3) + 8 * (r >> 2) + 4 * hi;
            opA[(size_t)row * DD] = accA[r] * llds[w][0][row];
            opB[(size_t)row * DD] = accB[r] * llds[w][1][row];
        }
    }
}

// ---------------- final: out = attn @ Wo + bo (split-bf16 for accuracy) ----------------
__global__ __launch_bounds__(256) void final_kernel(
    const float* __restrict__ attn,
    const short* __restrict__ WoTh, const short* __restrict__ WoTl,
    const float* __restrict__ bo, float* __restrict__ out)
{
    int tid = threadIdx.x;
    int lane = tid & 63, w = tid >> 6;
    int c = lane & 15, g = lane >> 4;
    int r0 = blockIdx.x * 64 + w * 16;
    int arow = r0 + c;

    short8 ah[6], al[6];
    #pragma unroll
    for (int kk = 0; kk < 6; kk++) {
        const float* pa = attn + (size_t)arow * DD + kk * 32 + g * 8;
        float4 f0 = *(const float4*)pa;
        float4 f1 = *(const float4*)(pa + 4);
        float fv[8] = {f0.x,f0.y,f0.z,f0.w,f1.x,f1.y,f1.z,f1.w};
        short8 th, tlo;
        #pragma unroll
        for (int j = 0; j < 8; j++) {
            short hi = nb(fv[j]);
            th[j] = hi;
            tlo[j] = nb(fv[j] - bf2f(hi));
        }
        ah[kk] = th; al[kk] = tlo;
    }

    f32x4 acc[12];
    #pragma unroll
    for (int n = 0; n < 12; n++) acc[n] = (f32x4){0.f,0.f,0.f,0.f};

    #pragma unroll
    for (int kk = 0; kk < 6; kk++) {
        #pragma unroll
        for (int n = 0; n < 12; n++) {
            const short* bh_p = WoTh + (size_t)(n*16 + c) * DD + kk * 32 + g * 8;
            const short* bl_p = WoTl + (size_t)(n*16 + c) * DD + kk * 32 + g * 8;
            short8 bh = *(const short8*)bh_p;
            short8 bl = *(const short8*)bl_p;
            acc[n] = MFMA16(ah[kk], bh, acc[n]);
            acc[n] = MFMA16(al[kk], bh, acc[n]);
            acc[n] = MFMA16(ah[kk], bl, acc[n]);
        }
    }

    #pragma unroll
    for (int n = 0; n < 12; n++) {
        int col = n*16 + c;
        float bv = bo[col];
        #pragma unroll
        for (int r = 0; r < 4; r++) {
            out[(size_t)(r0 + g*4 + r) * DD + col] = acc[n][r] + bv;
        }
    }
}

extern "C" void kernel_launch(void* const* d_in, const int* in_sizes, int n_in,
                              void* d_out, int out_size, void* d_ws, size_t ws_size,
                              hipStream_t stream)
{
    const float* x    = (const float*)d_in[0];
    const void*  mask = d_in[1];
    const float* Wq   = (const float*)d_in[2];
    const float* bq   = (const float*)d_in[3];
    const float* Wk   = (const float*)d_in[4];
    const float* bk   = (const float*)d_in[5];
    const float* Wv   = (const float*)d_in[6];
    const float* bv   = (const float*)d_in[7];
    const float* Wo   = (const float*)d_in[8];
    const float* bo   = (const float*)d_in[9];
    float* out = (float*)d_out;

    char* ws = (char*)d_ws;
    size_t off = 0;
    float* maskf = (float*)(ws + off); off += (size_t)BB*SS*4;          // 128 KB
    short* Q     = (short*)(ws + off); off += (size_t)BB*HH*SS*DHP*2;   // 16 MB
    short* K     = (short*)(ws + off); off += (size_t)BB*HH*SS*DHP*2;   // 16 MB
    short* Vt    = (short*)(ws + off); off += (size_t)BB*HH*SS*DHP*2;   // 16 MB
    float* attn  = (float*)(ws + off); off += (size_t)BB*SS*DD*4;       // 24 MB
    short* WqT   = (short*)(ws + off); off += (size_t)HH*DHP*DD*2;
    short* WkT   = (short*)(ws + off); off += (size_t)HH*DHP*DD*2;
    short* WvT   = (short*)(ws + off); off += (size_t)HH*DHP*DD*2;
    short* WoTh  = (short*)(ws + off); off += (size_t)DD*DD*2;
    short* WoTl  = (short*)(ws + off); off += (size_t)DD*DD*2;

    prep_kernel<<<dim3(848), dim3(256), 0, stream>>>(
        mask, Wq, Wk, Wv, Wo, maskf, WqT, WkT, WvT, WoTh, WoTl);
    proj_kernel<<<dim3(512), dim3(256), 0, stream>>>(
        x, bq, bk, bv, WqT, WkT, WvT, maskf, Q, K, Vt);
    flash_kernel<<<dim3(1024), dim3(256), 0, stream>>>(
        Q, K, Vt, attn);
    final_kernel<<<dim3(512), dim3(256), 0, stream>>>(
        attn, WoTh, WoTl, bo, out);
}

// Round 5
// 188.653 us; speedup vs baseline: 1.8257x; 1.0440x over previous
//
#include <hip/hip_runtime.h>

typedef __attribute__((ext_vector_type(8))) short short8;
typedef __attribute__((ext_vector_type(4))) short short4v;
typedef __attribute__((ext_vector_type(4))) float f32x4;
typedef __attribute__((ext_vector_type(16))) float f32x16;
typedef __attribute__((ext_vector_type(2))) unsigned uint2v;
typedef __attribute__((ext_vector_type(4))) unsigned uint4v;

#define MFMA16(a,b,c) __builtin_amdgcn_mfma_f32_16x16x32_bf16((a),(b),(c),0,0,0)
#define MFMA32(a,b,c) __builtin_amdgcn_mfma_f32_32x32x16_bf16((a),(b),(c),0,0,0)

#define BB 32
#define SS 1024
#define DD 192
#define HH 8
#define DHP 32   // padded head dim (24 -> 32); col 31 = mask-bias, col 24 of V = ones

// Q pre-scale: log2(e) / sqrt(24)  -> exp2(S) == softmax numerator
#define SCALE_Q 0.294468266742895f

// native RNE conversions (compiler emits v_cvt_*_bf16, fuses pairs to cvt_pk)
__device__ __forceinline__ short nb(float f) {
    __bf16 h = (__bf16)f;
    return __builtin_bit_cast(short, h);
}
__device__ __forceinline__ float bf2f(short s) {
    union { unsigned u; float f; } v; v.u = ((unsigned)(unsigned short)s) << 16;
    return v.f;
}
__device__ __forceinline__ unsigned pk2(float a, float b) {
    unsigned short lo = __builtin_bit_cast(unsigned short, (__bf16)a);
    unsigned short hi = __builtin_bit_cast(unsigned short, (__bf16)b);
    return (unsigned)lo | ((unsigned)hi << 16);
}

// ---------------- prep: mask normalize + weight transposes ----------------
// WqT/WkT/WvT rows within a head are PERMUTED: physical row p holds actual
// col e where p = (e>>1) | ((e&1)<<4)  (so proj pass nt, lane c -> col 2c+nt)
__global__ __launch_bounds__(256) void prep_kernel(
    const void* __restrict__ mask_raw,
    const float* __restrict__ Wq, const float* __restrict__ Wk, const float* __restrict__ Wv,
    const float* __restrict__ Wo,
    float* __restrict__ maskf,
    short* __restrict__ WqT, short* __restrict__ WkT, short* __restrict__ WvT,
    short* __restrict__ WoTh, short* __restrict__ WoTl)
{
    int idx = blockIdx.x * 256 + threadIdx.x;
    const int NMASK = BB * SS;               // 32768
    const int NWX   = 3 * HH * DHP * DD;     // 147456
    const int NWO   = DD * DD;               // 36864
    if (idx < NMASK) {
        // dtype sniff: bool may arrive as int32 (0/1), float32 (0.0/1.0) or uint8
        const unsigned* mw = (const unsigned*)mask_raw;
        bool all01 = true, allf = true;
        #pragma unroll
        for (int i = 0; i < 16; i++) {
            unsigned w = mw[i];
            all01 = all01 && (w <= 1u);
            allf  = allf  && (w == 0u || w == 0x3F800000u);
        }
        float m;
        if (all01)      m = (mw[idx] != 0u) ? 1.f : 0.f;
        else if (allf)  m = (((const float*)mask_raw)[idx] != 0.f) ? 1.f : 0.f;
        else            m = (((const unsigned char*)mask_raw)[idx] != 0) ? 1.f : 0.f;
        maskf[idx] = m;
    } else if (idx < NMASK + NWX) {
        int j = idx - NMASK;
        int mat = j / (HH * DHP * DD);
        int jj  = j % (HH * DHP * DD);
        int h   = jj / (DHP * DD);
        int rem = jj % (DHP * DD);
        int e   = rem / DD;       // actual output col
        int d   = rem % DD;
        const float* W = (mat == 0) ? Wq : (mat == 1) ? Wk : Wv;
        short* WT      = (mat == 0) ? WqT : (mat == 1) ? WkT : WvT;
        float val = (e < 24) ? W[(h * DD + d) * 24 + e] : 0.f;   // pad e>=24 with 0
        int p = (e >> 1) | ((e & 1) << 4);                       // permuted row
        WT[(h * DHP + p) * DD + d] = nb(val);
    } else if (idx < NMASK + NWX + NWO) {
        int j = idx - NMASK - NWX;
        int n = j / DD, k = j % DD;
        float f = Wo[k * DD + n];
        short hi = nb(f);
        WoTh[n * DD + k] = hi;
        WoTl[n * DD + k] = nb(f - bf2f(hi));   // split-bf16 low part
    }
}

// ---------------- proj: Q/K/V = x @ W + b via MFMA ----------------
// Q is pre-scaled by SCALE_Q, Q[:,31] = 1.0 (bias channel input)
// K[:,31]   = mask ? 0 : -1e30 (bias channel: QK^T gets -1e30 on masked k)
// V[:,24]   = 1.0 (ones column: PV MFMA computes softmax denominator for free)
__global__ __launch_bounds__(256) void proj_kernel(
    const float* __restrict__ x,
    const float* __restrict__ bq, const float* __restrict__ bk, const float* __restrict__ bv,
    const short* __restrict__ WqT, const short* __restrict__ WkT, const short* __restrict__ WvT,
    const float* __restrict__ maskf,
    short* __restrict__ Q, short* __restrict__ K, short* __restrict__ Vt)
{
    int tid = threadIdx.x;
    int lane = tid & 63, w = tid >> 6;
    int c = lane & 15, g = lane >> 4;
    int r0 = blockIdx.x * 64 + w * 16;
    int arow = r0 + c;

    // output row block for this thread: rows s0..s0+3 (same batch: 64 | 1024)
    int b_ = r0 >> 10;
    int s0 = (r0 & 1023) + g * 4;

    short8 a[6];
    #pragma unroll
    for (int kk = 0; kk < 6; kk++) {
        const float* px = x + (size_t)arow * DD + kk * 32 + g * 8;
        float4 f0 = *(const float4*)px;
        float4 f1 = *(const float4*)(px + 4);
        short8 t;
        t[0]=nb(f0.x); t[1]=nb(f0.y); t[2]=nb(f0.z); t[3]=nb(f0.w);
        t[4]=nb(f1.x); t[5]=nb(f1.y); t[6]=nb(f1.z); t[7]=nb(f1.w);
        a[kk] = t;
    }

    // mask values for this thread's 4 rows (only needed by c==15 for K)
    float mrow[4];
    #pragma unroll
    for (int r = 0; r < 4; r++) mrow[r] = maskf[b_ * SS + s0 + r];

    for (int h = 0; h < HH; h++) {
        int bh = b_ * HH + h;
        #pragma unroll
        for (int mat = 0; mat < 3; mat++) {
            const short* WT   = (mat==0)?WqT:(mat==1)?WkT:WvT;
            const float* bias = (mat==0)?bq:(mat==1)?bk:bv;

            f32x4 acc0 = {0.f,0.f,0.f,0.f};   // actual col 2c
            f32x4 acc1 = {0.f,0.f,0.f,0.f};   // actual col 2c+1
            const short* Wp0 = WT + (size_t)(h * DHP + c) * DD + g * 8;
            const short* Wp1 = WT + (size_t)(h * DHP + 16 + c) * DD + g * 8;
            #pragma unroll
            for (int kk = 0; kk < 6; kk++) {
                short8 b0 = *(const short8*)(Wp0 + kk * 32);
                short8 b1 = *(const short8*)(Wp1 + kk * 32);
                acc0 = MFMA16(a[kk], b0, acc0);
                acc1 = MFMA16(a[kk], b1, acc1);
            }
            // bias for cols 2c, 2c+1 (0 when >= 24)
            float bv0 = 0.f, bv1 = 0.f;
            if (2*c < 24) {
                float2 bb = *(const float2*)(bias + h * 24 + 2 * c);
                bv0 = bb.x; bv1 = bb.y;
            }

            if (mat == 0) {
                #pragma unroll
                for (int r = 0; r < 4; r++) {
                    float v0 = (acc0[r] + bv0) * SCALE_Q;
                    float v1 = (c == 15) ? 1.0f : (acc1[r] + bv1) * SCALE_Q;
                    *(unsigned*)(Q + ((size_t)bh * SS + s0 + r) * DHP + 2*c) = pk2(v0, v1);
                }
            } else if (mat == 1) {
                #pragma unroll
                for (int r = 0; r < 4; r++) {
                    float v0 = acc0[r] + bv0;
                    float v1 = (c == 15) ? ((mrow[r] != 0.f) ? 0.f : -1e30f)
                                         : (acc1[r] + bv1);
                    *(unsigned*)(K + ((size_t)bh * SS + s0 + r) * DHP + 2*c) = pk2(v0, v1);
                }
            } else {
                short4v sv0, sv1;
                #pragma unroll
                for (int r = 0; r < 4; r++) {
                    // col 24 (c==12, even slot) = ones column for denominator
                    sv0[r] = (c == 12) ? (short)0x3F80 : nb(acc0[r] + bv0);
                    sv1[r] = nb(acc1[r] + bv1);
                }
                *(short4v*)(Vt + ((size_t)bh * DHP + 2*c) * SS + s0)     = sv0;
                *(short4v*)(Vt + ((size_t)bh * DHP + 2*c + 1) * SS + s0) = sv1;
            }
        }
    }
}

// ---------------- flash attention (swapped QK^T, in-register softmax) ----------------
// exp2, pack to bf16, cross-half exchange via permlane32_swap, PV MFMA
__device__ __forceinline__ void fproc(const f32x16& S, f32x16& acc,
                                      short8 v0, short8 v1)
{
    float p[16];
    #pragma unroll
    for (int r = 0; r < 16; r++) p[r] = __builtin_amdgcn_exp2f(S[r]);

    // pack P pairs: lane (l31, hi) holds P[kpos = (r&3)+8*(r>>2)+4*hi][q = l31]
    unsigned c01 = pk2(p[0],  p[1]);   // kpos {0,1}+4hi
    unsigned c23 = pk2(p[2],  p[3]);   // kpos {2,3}+4hi
    unsigned c45 = pk2(p[4],  p[5]);   // kpos {8,9}+4hi
    unsigned c67 = pk2(p[6],  p[7]);   // kpos {10,11}+4hi
    unsigned c89 = pk2(p[8],  p[9]);   // kpos {16,17}+4hi
    unsigned cab = pk2(p[10], p[11]);  // kpos {18,19}+4hi
    unsigned ccd = pk2(p[12], p[13]);  // kpos {24,25}+4hi
    unsigned cef = pk2(p[14], p[15]);  // kpos {26,27}+4hi

    // permlane32_swap(a,b) -> x[l] = l<32 ? a[l] : b[l-32]
    //                         y[l] = l<32 ? a[l+32] : b[l]
    // matches the verified shfl/select construction exactly:
    // pa0 = { h1?o45:c01, h1?o67:c23, h1?c45:o01, h1?c67:o23 }
    uint2v s0 = __builtin_amdgcn_permlane32_swap(c01, c45, false, false);
    uint2v s1 = __builtin_amdgcn_permlane32_swap(c23, c67, false, false);
    uint2v s2 = __builtin_amdgcn_permlane32_swap(c89, ccd, false, false);
    uint2v s3 = __builtin_amdgcn_permlane32_swap(cab, cef, false, false);

    uint4v w0v = { s0.x, s1.x, s0.y, s1.y };   // PV A-frag, kpos tile 0..15
    uint4v w1v = { s2.x, s3.x, s2.y, s3.y };   // kpos tile 16..31
    short8 pa0 = __builtin_bit_cast(short8, w0v);
    short8 pa1 = __builtin_bit_cast(short8, w1v);

    acc = MFMA32(pa0, v0, acc);
    acc = MFMA32(pa1, v1, acc);
}

__global__ __launch_bounds__(256) void flash_kernel(
    const short* __restrict__ Q, const short* __restrict__ K, const short* __restrict__ Vt,
    short* __restrict__ attnb)
{
    __shared__ float llds[4][2][32];

    // consecutive idx = consecutive bh (round-robin XCD); the 4 q-blocks of
    // one bh are 256 apart -> same XCD (256 % 8 == 0) -> K/V L2 locality
    int idx = blockIdx.x;
    int bh = idx & 255;
    int qb = idx >> 8;          // 0..3
    int b = bh >> 3, h = bh & 7;

    int tid = threadIdx.x;
    int lane = tid & 63, w = tid >> 6;
    int l31 = lane & 31;
    int hi = lane >> 5;

    int qrA = qb * 256 + w * 32;
    int qrB = qrA + 128;

    // Q B-fragments (col = q = l31, k-dim = head-dim e), loop-invariant
    const short* QpA = Q + ((size_t)bh * SS + qrA + l31) * DHP + hi * 8;
    const short* QpB = Q + ((size_t)bh * SS + qrB + l31) * DHP + hi * 8;
    short8 qA0 = *(const short8*)QpA;          // e = hi*8 + j
    short8 qA1 = *(const short8*)(QpA + 16);   // e = 16 + hi*8 + j
    short8 qB0 = *(const short8*)QpB;
    short8 qB1 = *(const short8*)(QpB + 16);

    const short* Kp = K + ((size_t)bh * SS + l31) * DHP + hi * 8;
    const short* Vp = Vt + ((size_t)bh * DHP + l31) * SS + hi * 8;

    f32x16 accA, accB, Z16;
    #pragma unroll
    for (int r = 0; r < 16; r++) { accA[r] = 0.f; accB[r] = 0.f; Z16[r] = 0.f; }

    for (int kt = 0; kt < 32; kt++) {
        short8 k0 = *(const short8*)(Kp);        // A: row = kpos, kdim e 0..15
        short8 k1 = *(const short8*)(Kp + 16);   //                kdim e 16..31
        short8 v0 = *(const short8*)(Vp);        // B: col = e, k = kpos 0..15
        short8 v1 = *(const short8*)(Vp + 16);   //             k = kpos 16..31
        Kp += 32 * DHP;
        Vp += 32;

        // S[kpos][q]: col = q = l31, row = kpos = (r&3) + 8*(r>>2) + 4*hi
        // D != C on MFMA: seed with loop-invariant zero tuple (no mov burst)
        f32x16 SA = MFMA32(k0, qA0, Z16);
        SA = MFMA32(k1, qA1, SA);   // includes mask bias via channel e=31
        f32x16 SB = MFMA32(k0, qB0, Z16);
        SB = MFMA32(k1, qB1, SB);

        fproc(SA, accA, v0, v1);
        fproc(SB, accB, v0, v1);
    }

    // denominator came through V's ones-column: acc col 24 (lanes l31==24)
    if (l31 == 24) {
        #pragma unroll
        for (int r = 0; r < 16; r++) {
            int row = (r & 3) + 8 * (r >> 2) + 4 * hi;
            llds[w][0][row] = __builtin_amdgcn_rcpf(accA[r]);
            llds[w][1][row] = __builtin_amdgcn_rcpf(accB[r]);
        }
    }
    __builtin_amdgcn_wave_barrier();   // same-wave LDS ordering fence

    // O: col = e = l31, row = q = (r&3) + 8*(r>>2) + 4*hi
    if (l31 < 24) {
        short* opA = attnb + ((size_t)b * SS + qrA) * DD + h * 24 + l31;
        short* opB = attnb + ((size_t)b * SS + qrB) * DD + h * 24 + l31;
        #pragma unroll
        for (int r = 0; r < 16; r++) {
            int row = (r & 3) + 8 * (r >> 2) + 4 * hi;
            opA[(size_t)row * DD] = nb(accA[r] * llds[w][0][row]);
            opB[(size_t)row * DD] = nb(accB[r] * llds[w][1][row]);
        }
    }
}

// ---------------- final: out = attn(bf16) @ Wo + bo (Wo split hi+lo) ----------------
__global__ __launch_bounds__(256) void final_kernel(
    const short* __restrict__ attnb,
    const short* __restrict__ WoTh, const short* __restrict__ WoTl,
    const float* __restrict__ bo, float* __restrict__ out)
{
    int tid = threadIdx.x;
    int lane = tid & 63, w = tid >> 6;
    int c = lane & 15, g = lane >> 4;
    int r0 = blockIdx.x * 64 + w * 16;
    int arow = r0 + c;

    short8 a[6];
    #pragma unroll
    for (int kk = 0; kk < 6; kk++)
        a[kk] = *(const short8*)(attnb + (size_t)arow * DD + kk * 32 + g * 8);

    f32x4 acc[12];
    #pragma unroll
    for (int n = 0; n < 12; n++) acc[n] = (f32x4){0.f,0.f,0.f,0.f};

    #pragma unroll
    for (int kk = 0; kk < 6; kk++) {
        #pragma unroll
        for (int n = 0; n < 12; n++) {
            const short* bh_p = WoTh + (size_t)(n*16 + c) * DD + kk * 32 + g * 8;
            const short* bl_p = WoTl + (size_t)(n*16 + c) * DD + kk * 32 + g * 8;
            short8 bh = *(const short8*)bh_p;
            short8 bl = *(const short8*)bl_p;
            acc[n] = MFMA16(a[kk], bh, acc[n]);
            acc[n] = MFMA16(a[kk], bl, acc[n]);
        }
    }

    #pragma unroll
    for (int n = 0; n < 12; n++) {
        int col = n*16 + c;
        float bv = bo[col];
        #pragma unroll
        for (int r = 0; r < 4; r++) {
            out[(size_t)(r0 + g*4 + r) * DD + col] = acc[n][r] + bv;
        }
    }
}

extern "C" void kernel_launch(void* const* d_in, const int* in_sizes, int n_in,
                              void* d_out, int out_size, void* d_ws, size_t ws_size,
                              hipStream_t stream)
{
    const float* x    = (const float*)d_in[0];
    const void*  mask = d_in[1];
    const float* Wq   = (const float*)d_in[2];
    const float* bq   = (const float*)d_in[3];
    const float* Wk   = (const float*)d_in[4];
    const float* bk   = (const float*)d_in[5];
    const float* Wv   = (const float*)d_in[6];
    const float* bv   = (const float*)d_in[7];
    const float* Wo   = (const float*)d_in[8];
    const float* bo   = (const float*)d_in[9];
    float* out = (float*)d_out;

    char* ws = (char*)d_ws;
    size_t off = 0;
    float* maskf = (float*)(ws + off); off += (size_t)BB*SS*4;          // 128 KB
    short* Q     = (short*)(ws + off); off += (size_t)BB*HH*SS*DHP*2;   // 16 MB
    short* K     = (short*)(ws + off); off += (size_t)BB*HH*SS*DHP*2;   // 16 MB
    short* Vt    = (short*)(ws + off); off += (size_t)BB*HH*SS*DHP*2;   // 16 MB
    short* attnb = (short*)(ws + off); off += (size_t)BB*SS*DD*2;       // 12 MB
    short* WqT   = (short*)(ws + off); off += (size_t)HH*DHP*DD*2;
    short* WkT   = (short*)(ws + off); off += (size_t)HH*DHP*DD*2;
    short* WvT   = (short*)(ws + off); off += (size_t)HH*DHP*DD*2;
    short* WoTh  = (short*)(ws + off); off += (size_t)DD*DD*2;
    short* WoTl  = (short*)(ws + off); off += (size_t)DD*DD*2;

    prep_kernel<<<dim3(848), dim3(256), 0, stream>>>(
        mask, Wq, Wk, Wv, Wo, maskf, WqT, WkT, WvT, WoTh, WoTl);
    proj_kernel<<<dim3(512), dim3(256), 0, stream>>>(
        x, bq, bk, bv, WqT, WkT, WvT, maskf, Q, K, Vt);
    flash_kernel<<<dim3(1024), dim3(256), 0, stream>>>(
        Q, K, Vt, attnb);
    final_kernel<<<dim3(512), dim3(256), 0, stream>>>(
        attnb, WoTh, WoTl, bo, out);
}